// Round 3
// baseline (151.621 us; speedup 1.0000x reference)
//
#include <hip/hip_runtime.h>
#include <hip/hip_bf16.h>

#define NN 256
#define FI 128
#define FO 64
#define LOG2E 1.4426950408889634f

typedef short s16x8 __attribute__((ext_vector_type(8)));
typedef float f32x4 __attribute__((ext_vector_type(4)));

__device__ __forceinline__ unsigned f2bf1(float x) {
  union { float f; unsigned u; } v; v.f = x;
  unsigned r = v.u + 0x7FFFu + ((v.u >> 16) & 1u);
  return r >> 16;
}
__device__ __forceinline__ unsigned pack2(float a, float b) {
  return f2bf1(a) | (f2bf1(b) << 16);
}
// one-instruction bf16x2 pack (truncation) via v_perm_b32 — alpha only
__device__ __forceinline__ unsigned pktrunc(float lo, float hi) {
  union { float f; unsigned u; } a, b; a.f = hi; b.f = lo;
  return __builtin_amdgcn_perm(a.u, b.u, 0x07060302u);
}
__device__ __forceinline__ float fexp2(float x) {
#if __has_builtin(__builtin_amdgcn_exp2f)
  return __builtin_amdgcn_exp2f(x);
#else
  return exp2f(x);
#endif
}

// ---------------- Kernel 0: adj -> 256-bit row bitmasks, plus W -> bf16 W^T
__global__ __launch_bounds__(256) void gat_k0(const float* __restrict__ adj,
                                              const float* __restrict__ W,
                                              unsigned* __restrict__ msk,
                                              unsigned short* __restrict__ WTbf) {
  const int b = blockIdx.x;
  if (b < NN) {
    const int row = b;
    const int wv = threadIdx.x >> 6, lane = threadIdx.x & 63;
    float v = adj[row * NN + wv * 64 + lane];
    unsigned long long bb = __ballot(v > 0.f);
    if (lane == 0) {
      msk[row * 8 + wv * 2]     = (unsigned)bb;
      msk[row * 8 + wv * 2 + 1] = (unsigned)(bb >> 32);
    }
  } else {
    // W[k][o] (fp32, 128x64) -> WTbf[o][k] (bf16, 64x128)
    for (int idx = threadIdx.x; idx < FI * FO; idx += 256) {
      int k = idx >> 6, o = idx & 63;
      WTbf[o * FI + k] = (unsigned short)f2bf1(W[idx]);
    }
  }
}

// ---------------- Kernel A: GEMM-1. Zero LDS, zero barriers.
// 256 threads = 4 waves; each wave owns ONE 16-row subtile of Wh.
// grid = 512 graphs * 4 quarters. Writes:
//   whG  : bf16 Wh in GEMM-2 fragment-chunk layout (32 KB/graph)
//   wh1G/wh2G : fp32, pre-scaled by LOG2E
__global__ __launch_bounds__(256, 4)
void gat_wh(const float* __restrict__ h, const unsigned short* __restrict__ WTbf,
            const float* __restrict__ a,
            unsigned short* __restrict__ whG,
            float* __restrict__ wh1G, float* __restrict__ wh2G)
{
  const int bid  = blockIdx.x;
  const int g    = bid >> 2;          // graph (b*t)
  const int qt   = bid & 3;           // quarter: rows 64*qt..+63
  const int tid  = threadIdx.x;
  const int lane = tid & 63;
  const int w2   = tid >> 6;          // wave 0..3
  const int m    = lane & 15;
  const int q    = lane >> 4;
  const int R    = 64 * qt + 16 * w2; // wave's 16-row base (16-aligned)

  const float* __restrict__ hB = h + (size_t)g * NN * FI;

  // 16 rows of h: lane (m,q) -> row R+m, cols kt*32 + q*8 (+0,+4). All issued up front.
  float4 x[4][2];
  #pragma unroll
  for (int kt = 0; kt < 4; ++kt) {
    const float* p = hB + (size_t)(R + m) * FI + kt * 32 + q * 8;
    x[kt][0] = *(const float4*)p;
    x[kt][1] = *(const float4*)(p + 4);
  }

  // a-vector values (512 B, L1-broadcast)
  float a1v[4], a2v[4];
  #pragma unroll
  for (int nt = 0; nt < 4; ++nt) {
    a1v[nt] = a[16 * nt + m];
    a2v[nt] = a[FO + 16 * nt + m];
  }

  s16x8 af[4];
  #pragma unroll
  for (int kt = 0; kt < 4; ++kt) {
    union { unsigned u[4]; s16x8 v; } pk;
    pk.u[0] = pack2(x[kt][0].x, x[kt][0].y);
    pk.u[1] = pack2(x[kt][0].z, x[kt][0].w);
    pk.u[2] = pack2(x[kt][1].x, x[kt][1].y);
    pk.u[3] = pack2(x[kt][1].z, x[kt][1].w);
    af[kt] = pk.v;
  }

  f32x4 acc[4];
  #pragma unroll
  for (int nt = 0; nt < 4; ++nt) acc[nt] = (f32x4){0.f, 0.f, 0.f, 0.f};
  #pragma unroll
  for (int kt = 0; kt < 4; ++kt)
    #pragma unroll
    for (int nt = 0; nt < 4; ++nt) {
      // W^T bf16 fragment straight from global (16 KB, L1-resident)
      s16x8 bf = *(const s16x8*)&WTbf[(16 * nt + m) * FI + kt * 32 + q * 8];
      acc[nt] = __builtin_amdgcn_mfma_f32_16x16x32_bf16(af[kt], bf, acc[nt], 0, 0, 0);
    }

  // wh1/wh2 epilogue (acc[nt][r] = Wh[R+4q+r][16nt+m]); store x log2e
  {
    float p1[4] = {0.f,0.f,0.f,0.f}, p2[4] = {0.f,0.f,0.f,0.f};
    #pragma unroll
    for (int nt = 0; nt < 4; ++nt) {
      #pragma unroll
      for (int r = 0; r < 4; ++r) { p1[r] += acc[nt][r] * a1v[nt]; p2[r] += acc[nt][r] * a2v[nt]; }
    }
    #pragma unroll
    for (int off = 1; off < 16; off <<= 1)
      #pragma unroll
      for (int r = 0; r < 4; ++r) {
        p1[r] += __shfl_xor(p1[r], off);
        p2[r] += __shfl_xor(p2[r], off);
      }
    if (m == 0) {
      *(float4*)&wh1G[g * NN + R + 4 * q] =
          make_float4(p1[0]*LOG2E, p1[1]*LOG2E, p1[2]*LOG2E, p1[3]*LOG2E);
      *(float4*)&wh2G[g * NN + R + 4 * q] =
          make_float4(p2[0]*LOG2E, p2[1]*LOG2E, p2[2]*LOG2E, p2[3]*LOG2E);
    }
  }

  // Wh -> global frag-chunk layout (NO xor swizzle: global has no banks; the
  // read side drops it too). chunk = ((Wv*4+nt)*16+m)*4 + qB, 16B chunks.
  // Per nt the wave's 64 lanes write one contiguous 512 B run (8B/lane).
  {
    const int Wv = R >> 5;          // 0..7 (matches GEMM-2's kt)
    const int S  = (R >> 4) & 1;
    const int qB = (2 * S + (q >> 1)) & 3;
    unsigned short* whP = whG + (size_t)g * (NN * FO);
    #pragma unroll
    for (int nt = 0; nt < 4; ++nt) {
      int chunk = ((Wv * 4 + nt) * 16 + m) * 4 + qB;
      uint2 wrv;
      wrv.x = pack2(acc[nt][0], acc[nt][1]);
      wrv.y = pack2(acc[nt][2], acc[nt][3]);
      *(uint2*)((char*)whP + chunk * 16 + (q & 1) * 8) = wrv;
    }
  }
}

// ---------------- Kernel B: softmax + GEMM-2 + elu. Zero LDS, zero barriers.
// 256 threads = 4 waves; each wave owns 16 attention rows.
// grid = 512 graphs * 4 quarters. Wh fragments read lane-linear from whG
// (wave reads a contiguous 1 KB per (kt,ot); 32 KB/graph, L2-resident).
__global__ __launch_bounds__(256, 4)
void gat_attn(const unsigned short* __restrict__ whG,
              const float* __restrict__ wh1G, const float* __restrict__ wh2G,
              const unsigned* __restrict__ msk, float* __restrict__ out)
{
  const int bid  = blockIdx.x;
  const int g    = bid >> 2;
  const int qt   = bid & 3;
  const int tid  = threadIdx.x;
  const int lane = tid & 63;
  const int w2   = tid >> 6;
  const int m    = lane & 15;
  const int q    = lane >> 4;
  const int row  = 64 * qt + 16 * w2 + m;   // this lane's attention row

  const unsigned short* __restrict__ whP = whG + (size_t)g * (NN * FO);
  const float* __restrict__ wh2B = wh2G + g * NN;

  const uint4 mka = *(const uint4*)&msk[row * 8];
  const uint4 mkb = *(const uint4*)&msk[row * 8 + 4];
  const unsigned mkw[8] = {mka.x, mka.y, mka.z, mka.w, mkb.x, mkb.y, mkb.z, mkb.w};
  const float w1 = wh1G[g * NN + row];      // pre-scaled by log2e

  s16x8 A[8];                               // alpha, B-fragment layout
  float sum = 0.f;
  #pragma unroll
  for (int kt = 0; kt < 8; ++kt) {
    int j0 = kt * 32 + q * 8;
    float4 w20 = *(const float4*)&wh2B[j0];
    float4 w21 = *(const float4*)&wh2B[j0 + 4];
    unsigned wq = mkw[kt] >> (q * 8);
    float p[8];
    const float w2e[8] = {w20.x, w20.y, w20.z, w20.w, w21.x, w21.y, w21.z, w21.w};
    #pragma unroll
    for (int e = 0; e < 8; ++e) {
      float l = w1 + w2e[e];
      l = fmaxf(l, 0.01f * l);                 // leaky-relu (log2e pre-folded)
      union { float f; int i; } u_; u_.f = fexp2(l);
      u_.i &= ((int)(wq << (31 - e))) >> 31;   // adj bit -> 0 / all-ones
      p[e] = u_.f;
      sum += u_.f;
    }
    union { unsigned u[4]; s16x8 v; } pk;
    pk.u[0] = pktrunc(p[0], p[1]);
    pk.u[1] = pktrunc(p[2], p[3]);
    pk.u[2] = pktrunc(p[4], p[5]);
    pk.u[3] = pktrunc(p[6], p[7]);
    A[kt] = pk.v;
  }
  sum += __shfl_xor(sum, 16);
  sum += __shfl_xor(sum, 32);
  const float inv = __builtin_amdgcn_rcpf(sum);

  // GEMM-2 swapped: D = Wh^T(A-op) @ alpha^T(B-op).
  f32x4 acc[4];
  #pragma unroll
  for (int ot = 0; ot < 4; ++ot) acc[ot] = (f32x4){0.f, 0.f, 0.f, 0.f};
  #pragma unroll
  for (int kt = 0; kt < 8; ++kt) {
    #pragma unroll
    for (int ot = 0; ot < 4; ++ot) {
      int chunk = ((kt * 4 + ot) * 16 + m) * 4 + q;   // linear, no xor
      s16x8 whf = *(const s16x8*)&whP[chunk * 8];
      acc[ot] = __builtin_amdgcn_mfma_f32_16x16x32_bf16(whf, A[kt], acc[ot], 0, 0, 0);
    }
  }

  // epilogue: lane(m,q) holds out[row][16ot+4q .. +3]
  float* outB = out + (size_t)g * NN * FO;
  #pragma unroll
  for (int ot = 0; ot < 4; ++ot) {
    float4 v4;
    float* vp = (float*)&v4;
    #pragma unroll
    for (int r = 0; r < 4; ++r) {
      float v = acc[ot][r] * inv;
      float ev = fexp2(v * LOG2E) - 1.f;
      vp[r] = v > 0.f ? v : ev;
    }
    *(float4*)&outB[row * FO + 16 * ot + 4 * q] = v4;
  }
}

extern "C" void kernel_launch(void* const* d_in, const int* in_sizes, int n_in,
                              void* d_out, int out_size, void* d_ws, size_t ws_size,
                              hipStream_t stream) {
  const float* h   = (const float*)d_in[0];
  const float* W   = (const float*)d_in[1];
  const float* a   = (const float*)d_in[2];
  const float* adj = (const float*)d_in[3];
  float* out = (float*)d_out;

  // workspace layout (all 16B-aligned):
  //   msk  : 8 KiB
  //   WTbf : 16 KiB (bf16 W^T [o][k])
  //   wh1G : 512 KiB
  //   wh2G : 512 KiB
  //   whG  : 16 MiB (bf16 Wh, frag-chunk layout, 32 KB/graph)
  char* ws = (char*)d_ws;
  unsigned*        msk  = (unsigned*)(ws);
  unsigned short*  WTbf = (unsigned short*)(ws + 8192);
  float*           wh1G = (float*)(ws + 8192 + 16384);
  float*           wh2G = (float*)(ws + 8192 + 16384 + 524288);
  unsigned short*  whG  = (unsigned short*)(ws + 8192 + 16384 + 2 * 524288);

  gat_k0  <<<dim3(NN + 1), dim3(256), 0, stream>>>(adj, W, msk, WTbf);
  gat_wh  <<<dim3(2048),   dim3(256), 0, stream>>>(h, WTbf, a, whG, wh1G, wh2G);
  gat_attn<<<dim3(2048),   dim3(256), 0, stream>>>(whG, wh1G, wh2G, msk, out);
}

// Round 5
// 146.580 us; speedup vs baseline: 1.0344x; 1.0344x over previous
//
#include <hip/hip_runtime.h>
#include <hip/hip_bf16.h>

#define NN 256
#define FI 128
#define FO 64
#define LOG2E 1.4426950408889634f

typedef short s16x8 __attribute__((ext_vector_type(8)));
typedef float f32x4 __attribute__((ext_vector_type(4)));

__device__ __forceinline__ unsigned f2bf1(float x) {
  union { float f; unsigned u; } v; v.f = x;
  unsigned r = v.u + 0x7FFFu + ((v.u >> 16) & 1u);
  return r >> 16;
}
__device__ __forceinline__ unsigned pack2(float a, float b) {
  return f2bf1(a) | (f2bf1(b) << 16);
}
// one-instruction bf16x2 pack (truncation) via v_perm_b32 — alpha only
__device__ __forceinline__ unsigned pktrunc(float lo, float hi) {
  union { float f; unsigned u; } a, b; a.f = hi; b.f = lo;
  return __builtin_amdgcn_perm(a.u, b.u, 0x07060302u);
}
__device__ __forceinline__ float fexp2(float x) {
#if __has_builtin(__builtin_amdgcn_exp2f)
  return __builtin_amdgcn_exp2f(x);
#else
  return exp2f(x);
#endif
}

// ---------------- Kernel A: GEMM-1. One barrier, 17 KB LDS (W^T staging).
// 256 threads = 4 waves; each wave owns ONE 16-row subtile of Wh.
// grid = 512 graphs * 4 quarters. Writes:
//   whG  : bf16 Wh in GEMM-2 fragment-chunk layout (32 KB/graph)
//   wh1G/wh2G : fp32, pre-scaled by LOG2E
__global__ __launch_bounds__(256, 4)
void gat_wh(const float* __restrict__ h, const float* __restrict__ W,
            const float* __restrict__ a,
            unsigned short* __restrict__ whG,
            float* __restrict__ wh1G, float* __restrict__ wh2G)
{
  const int bid  = blockIdx.x;
  const int g    = bid >> 2;          // graph (b*t)
  const int qt   = bid & 3;           // quarter: rows 64*qt..+63
  const int tid  = threadIdx.x;
  const int lane = tid & 63;
  const int w2   = tid >> 6;          // wave 0..3
  const int m    = lane & 15;
  const int q    = lane >> 4;
  const int R    = 64 * qt + 16 * w2; // wave's 16-row base (16-aligned)

  __shared__ __align__(16) unsigned short sWT[64 * 136]; // bf16 W^T [o][k], padded

  const float* __restrict__ hB = h + (size_t)g * NN * FI;

  // 16 rows of h: lane (m,q) -> row R+m, cols kt*32 + q*8 (+0,+4). Issued up front.
  float4 x[4][2];
  #pragma unroll
  for (int kt = 0; kt < 4; ++kt) {
    const float* p = hB + (size_t)(R + m) * FI + kt * 32 + q * 8;
    x[kt][0] = *(const float4*)p;
    x[kt][1] = *(const float4*)(p + 4);
  }

  // Stage W (fp32 [k][o], 32 KB, L2-hot) -> sWT bf16 [o][k].
  // 8 iters x 256 thr x 4 elems = 8192 = FI*FO.
  #pragma unroll
  for (int it = 0; it < 8; ++it) {
    int idx4 = (it * 256 + tid) * 4;
    int k = idx4 >> 6, o = idx4 & 63;
    float4 wv = *(const float4*)&W[idx4];
    sWT[(o + 0) * 136 + k] = (unsigned short)f2bf1(wv.x);
    sWT[(o + 1) * 136 + k] = (unsigned short)f2bf1(wv.y);
    sWT[(o + 2) * 136 + k] = (unsigned short)f2bf1(wv.z);
    sWT[(o + 3) * 136 + k] = (unsigned short)f2bf1(wv.w);
  }

  // a-vector values (512 B, L1-broadcast)
  float a1v[4], a2v[4];
  #pragma unroll
  for (int nt = 0; nt < 4; ++nt) {
    a1v[nt] = a[16 * nt + m];
    a2v[nt] = a[FO + 16 * nt + m];
  }

  s16x8 af[4];
  #pragma unroll
  for (int kt = 0; kt < 4; ++kt) {
    union { unsigned u[4]; s16x8 v; } pk;
    pk.u[0] = pack2(x[kt][0].x, x[kt][0].y);
    pk.u[1] = pack2(x[kt][0].z, x[kt][0].w);
    pk.u[2] = pack2(x[kt][1].x, x[kt][1].y);
    pk.u[3] = pack2(x[kt][1].z, x[kt][1].w);
    af[kt] = pk.v;
  }

  __syncthreads();   // sWT ready

  f32x4 acc[4];
  #pragma unroll
  for (int nt = 0; nt < 4; ++nt) acc[nt] = (f32x4){0.f, 0.f, 0.f, 0.f};
  #pragma unroll
  for (int kt = 0; kt < 4; ++kt)
    #pragma unroll
    for (int nt = 0; nt < 4; ++nt) {
      s16x8 bf = *(const s16x8*)&sWT[(16 * nt + m) * 136 + kt * 32 + q * 8];
      acc[nt] = __builtin_amdgcn_mfma_f32_16x16x32_bf16(af[kt], bf, acc[nt], 0, 0, 0);
    }

  // wh1/wh2 epilogue (acc[nt][r] = Wh[R+4q+r][16nt+m]); store x log2e
  {
    float p1[4] = {0.f,0.f,0.f,0.f}, p2[4] = {0.f,0.f,0.f,0.f};
    #pragma unroll
    for (int nt = 0; nt < 4; ++nt) {
      #pragma unroll
      for (int r = 0; r < 4; ++r) { p1[r] += acc[nt][r] * a1v[nt]; p2[r] += acc[nt][r] * a2v[nt]; }
    }
    #pragma unroll
    for (int off = 1; off < 16; off <<= 1)
      #pragma unroll
      for (int r = 0; r < 4; ++r) {
        p1[r] += __shfl_xor(p1[r], off);
        p2[r] += __shfl_xor(p2[r], off);
      }
    if (m == 0) {
      *(float4*)&wh1G[g * NN + R + 4 * q] =
          make_float4(p1[0]*LOG2E, p1[1]*LOG2E, p1[2]*LOG2E, p1[3]*LOG2E);
      *(float4*)&wh2G[g * NN + R + 4 * q] =
          make_float4(p2[0]*LOG2E, p2[1]*LOG2E, p2[2]*LOG2E, p2[3]*LOG2E);
    }
  }

  // Wh -> global frag-chunk layout (linear, no xor: global has no banks; the
  // read side matches). chunk = ((Wv*4+nt)*16+m)*4 + qB, 16B chunks.
  {
    const int Wv = R >> 5;          // 0..7 (matches GEMM-2's kt)
    const int S  = (R >> 4) & 1;
    const int qB = (2 * S + (q >> 1)) & 3;
    unsigned short* whP = whG + (size_t)g * (NN * FO);
    #pragma unroll
    for (int nt = 0; nt < 4; ++nt) {
      int chunk = ((Wv * 4 + nt) * 16 + m) * 4 + qB;
      uint2 wrv;
      wrv.x = pack2(acc[nt][0], acc[nt][1]);
      wrv.y = pack2(acc[nt][2], acc[nt][3]);
      *(uint2*)((char*)whP + chunk * 16 + (q & 1) * 8) = wrv;
    }
  }
}

// ---------------- Kernel B: softmax + GEMM-2 + elu. Zero LDS, zero barriers.
// 256 threads = 4 waves; each wave owns 16 attention rows.
// grid = 512 graphs * 4 quarters. Wh fragments read lane-linear from whG
// (wave reads a contiguous 1 KB per (kt,ot); 32 KB/graph, L2-resident).
// Masking reads adj directly (256 KB shared by ALL graphs, L2-hot; values are
// exactly 0.0/1.0 so mask = multiply — no bitmask kernel needed).
__global__ __launch_bounds__(256, 4)
void gat_attn(const unsigned short* __restrict__ whG,
              const float* __restrict__ wh1G, const float* __restrict__ wh2G,
              const float* __restrict__ adj, float* __restrict__ out)
{
  const int bid  = blockIdx.x;
  const int g    = bid >> 2;
  const int qt   = bid & 3;
  const int tid  = threadIdx.x;
  const int lane = tid & 63;
  const int w2   = tid >> 6;
  const int m    = lane & 15;
  const int q    = lane >> 4;
  const int row  = 64 * qt + 16 * w2 + m;   // this lane's attention row

  const unsigned short* __restrict__ whP = whG + (size_t)g * (NN * FO);
  const float* __restrict__ wh2B = wh2G + g * NN;
  const float* __restrict__ adjR = adj + (size_t)row * NN;

  const float w1 = wh1G[g * NN + row];      // pre-scaled by log2e

  s16x8 A[8];                               // alpha, B-fragment layout
  float sum = 0.f;
  #pragma unroll
  for (int kt = 0; kt < 8; ++kt) {
    int j0 = kt * 32 + q * 8;
    float4 w20 = *(const float4*)&wh2B[j0];
    float4 w21 = *(const float4*)&wh2B[j0 + 4];
    float4 ad0 = *(const float4*)&adjR[j0];
    float4 ad1 = *(const float4*)&adjR[j0 + 4];
    float p[8];
    const float w2e[8] = {w20.x, w20.y, w20.z, w20.w, w21.x, w21.y, w21.z, w21.w};
    const float ade[8] = {ad0.x, ad0.y, ad0.z, ad0.w, ad1.x, ad1.y, ad1.z, ad1.w};
    #pragma unroll
    for (int e = 0; e < 8; ++e) {
      float l = w1 + w2e[e];
      l = fmaxf(l, 0.01f * l);               // leaky-relu (log2e pre-folded)
      float pe = fexp2(l) * ade[e];          // adj is exactly 0.0/1.0 -> mask=mul
      p[e] = pe;
      sum += pe;
    }
    union { unsigned u[4]; s16x8 v; } pk;
    pk.u[0] = pktrunc(p[0], p[1]);
    pk.u[1] = pktrunc(p[2], p[3]);
    pk.u[2] = pktrunc(p[4], p[5]);
    pk.u[3] = pktrunc(p[6], p[7]);
    A[kt] = pk.v;
  }
  sum += __shfl_xor(sum, 16);
  sum += __shfl_xor(sum, 32);
  const float inv = __builtin_amdgcn_rcpf(sum);

  // GEMM-2 swapped: D = Wh^T(A-op) @ alpha^T(B-op).
  f32x4 acc[4];
  #pragma unroll
  for (int ot = 0; ot < 4; ++ot) acc[ot] = (f32x4){0.f, 0.f, 0.f, 0.f};
  #pragma unroll
  for (int kt = 0; kt < 8; ++kt) {
    #pragma unroll
    for (int ot = 0; ot < 4; ++ot) {
      int chunk = ((kt * 4 + ot) * 16 + m) * 4 + q;   // linear
      s16x8 whf = *(const s16x8*)&whP[chunk * 8];
      acc[ot] = __builtin_amdgcn_mfma_f32_16x16x32_bf16(whf, A[kt], acc[ot], 0, 0, 0);
    }
  }

  // epilogue: lane(m,q) holds out[row][16ot+4q .. +3]
  float* outB = out + (size_t)g * NN * FO;
  #pragma unroll
  for (int ot = 0; ot < 4; ++ot) {
    float4 v4;
    float* vp = (float*)&v4;
    #pragma unroll
    for (int r = 0; r < 4; ++r) {
      float v = acc[ot][r] * inv;
      float ev = fexp2(v * LOG2E) - 1.f;
      vp[r] = v > 0.f ? v : ev;
    }
    *(float4*)&outB[row * FO + 16 * ot + 4 * q] = v4;
  }
}

extern "C" void kernel_launch(void* const* d_in, const int* in_sizes, int n_in,
                              void* d_out, int out_size, void* d_ws, size_t ws_size,
                              hipStream_t stream) {
  const float* h   = (const float*)d_in[0];
  const float* W   = (const float*)d_in[1];
  const float* a   = (const float*)d_in[2];
  const float* adj = (const float*)d_in[3];
  float* out = (float*)d_out;

  // workspace layout (all 16B-aligned):
  //   wh1G : 512 KiB   (fp32, pre-scaled by log2e)
  //   wh2G : 512 KiB
  //   whG  : 16 MiB    (bf16 Wh, frag-chunk layout, 32 KB/graph)
  char* ws = (char*)d_ws;
  float*           wh1G = (float*)(ws);
  float*           wh2G = (float*)(ws + 524288);
  unsigned short*  whG  = (unsigned short*)(ws + 2 * 524288);

  gat_wh  <<<dim3(2048), dim3(256), 0, stream>>>(h, W, a, whG, wh1G, wh2G);
  gat_attn<<<dim3(2048), dim3(256), 0, stream>>>(whG, wh1G, wh2G, adj, out);
}

// Round 6
// 134.749 us; speedup vs baseline: 1.1252x; 1.0878x over previous
//
#include <hip/hip_runtime.h>
#include <hip/hip_bf16.h>

#define NN 256
#define FI 128
#define FO 64
#define LOG2E 1.4426950408889634f

typedef short s16x8 __attribute__((ext_vector_type(8)));
typedef float f32x4 __attribute__((ext_vector_type(4)));

__device__ __forceinline__ unsigned f2bf1(float x) {
  union { float f; unsigned u; } v; v.f = x;
  unsigned r = v.u + 0x7FFFu + ((v.u >> 16) & 1u);
  return r >> 16;
}
__device__ __forceinline__ unsigned pack2(float a, float b) {
  return f2bf1(a) | (f2bf1(b) << 16);
}
// one-instruction bf16x2 pack (truncation) via v_perm_b32 — alpha only
__device__ __forceinline__ unsigned pktrunc(float lo, float hi) {
  union { float f; unsigned u; } a, b; a.f = hi; b.f = lo;
  return __builtin_amdgcn_perm(a.u, b.u, 0x07060302u);
}
__device__ __forceinline__ float fexp2(float x) {
#if __has_builtin(__builtin_amdgcn_exp2f)
  return __builtin_amdgcn_exp2f(x);
#else
  return exp2f(x);
#endif
}

// ---------------- Kernel A: GEMM-1. One barrier, 17 KB LDS (W^T staging).
// 256 threads = 4 waves; each wave owns ONE 16-row subtile of Wh.
// grid = 512 graphs * 4 quarters. Writes:
//   whG  : bf16 Wh in GEMM-2 fragment-chunk layout (32 KB/graph),
//          q-slot swizzled by (m&3)^((m>>2)&3) so kernel B's LDS reads are 2-way
//   wh1G/wh2G : fp32, pre-scaled by LOG2E
__global__ __launch_bounds__(256, 4)
void gat_wh(const float* __restrict__ h, const float* __restrict__ W,
            const float* __restrict__ a,
            unsigned short* __restrict__ whG,
            float* __restrict__ wh1G, float* __restrict__ wh2G)
{
  const int bid  = blockIdx.x;
  const int g    = bid >> 2;          // graph (b*t)
  const int qt   = bid & 3;           // quarter: rows 64*qt..+63
  const int tid  = threadIdx.x;
  const int lane = tid & 63;
  const int w2   = tid >> 6;          // wave 0..3
  const int m    = lane & 15;
  const int q    = lane >> 4;
  const int R    = 64 * qt + 16 * w2; // wave's 16-row base (16-aligned)

  __shared__ __align__(16) unsigned short sWT[64 * 136]; // bf16 W^T [o][k], padded

  const float* __restrict__ hB = h + (size_t)g * NN * FI;

  // 16 rows of h: lane (m,q) -> row R+m, cols kt*32 + q*8 (+0,+4). Issued up front.
  float4 x[4][2];
  #pragma unroll
  for (int kt = 0; kt < 4; ++kt) {
    const float* p = hB + (size_t)(R + m) * FI + kt * 32 + q * 8;
    x[kt][0] = *(const float4*)p;
    x[kt][1] = *(const float4*)(p + 4);
  }

  // Stage W (fp32 [k][o], 32 KB, L2-hot) -> sWT bf16 [o][k].
  // 8 iters x 256 thr x 4 elems = 8192 = FI*FO.
  #pragma unroll
  for (int it = 0; it < 8; ++it) {
    int idx4 = (it * 256 + tid) * 4;
    int k = idx4 >> 6, o = idx4 & 63;
    float4 wv = *(const float4*)&W[idx4];
    sWT[(o + 0) * 136 + k] = (unsigned short)f2bf1(wv.x);
    sWT[(o + 1) * 136 + k] = (unsigned short)f2bf1(wv.y);
    sWT[(o + 2) * 136 + k] = (unsigned short)f2bf1(wv.z);
    sWT[(o + 3) * 136 + k] = (unsigned short)f2bf1(wv.w);
  }

  // a-vector values (512 B, L1-broadcast)
  float a1v[4], a2v[4];
  #pragma unroll
  for (int nt = 0; nt < 4; ++nt) {
    a1v[nt] = a[16 * nt + m];
    a2v[nt] = a[FO + 16 * nt + m];
  }

  s16x8 af[4];
  #pragma unroll
  for (int kt = 0; kt < 4; ++kt) {
    union { unsigned u[4]; s16x8 v; } pk;
    pk.u[0] = pack2(x[kt][0].x, x[kt][0].y);
    pk.u[1] = pack2(x[kt][0].z, x[kt][0].w);
    pk.u[2] = pack2(x[kt][1].x, x[kt][1].y);
    pk.u[3] = pack2(x[kt][1].z, x[kt][1].w);
    af[kt] = pk.v;
  }

  __syncthreads();   // sWT ready

  f32x4 acc[4];
  #pragma unroll
  for (int nt = 0; nt < 4; ++nt) acc[nt] = (f32x4){0.f, 0.f, 0.f, 0.f};
  #pragma unroll
  for (int kt = 0; kt < 4; ++kt)
    #pragma unroll
    for (int nt = 0; nt < 4; ++nt) {
      s16x8 bf = *(const s16x8*)&sWT[(16 * nt + m) * 136 + kt * 32 + q * 8];
      acc[nt] = __builtin_amdgcn_mfma_f32_16x16x32_bf16(af[kt], bf, acc[nt], 0, 0, 0);
    }

  // wh1/wh2 epilogue (acc[nt][r] = Wh[R+4q+r][16nt+m]); store x log2e
  {
    float p1[4] = {0.f,0.f,0.f,0.f}, p2[4] = {0.f,0.f,0.f,0.f};
    #pragma unroll
    for (int nt = 0; nt < 4; ++nt) {
      #pragma unroll
      for (int r = 0; r < 4; ++r) { p1[r] += acc[nt][r] * a1v[nt]; p2[r] += acc[nt][r] * a2v[nt]; }
    }
    #pragma unroll
    for (int off = 1; off < 16; off <<= 1)
      #pragma unroll
      for (int r = 0; r < 4; ++r) {
        p1[r] += __shfl_xor(p1[r], off);
        p2[r] += __shfl_xor(p2[r], off);
      }
    if (m == 0) {
      *(float4*)&wh1G[g * NN + R + 4 * q] =
          make_float4(p1[0]*LOG2E, p1[1]*LOG2E, p1[2]*LOG2E, p1[3]*LOG2E);
      *(float4*)&wh2G[g * NN + R + 4 * q] =
          make_float4(p2[0]*LOG2E, p2[1]*LOG2E, p2[2]*LOG2E, p2[3]*LOG2E);
    }
  }

  // Wh -> global frag-chunk layout, q-slot PRE-SWIZZLED for kernel B's LDS
  // bank pattern (rule #21: swizzled source + linear LDS copy + swizzled read).
  // chunk = ((Wv*4+nt)*16+m)*4 + (qB ^ (m&3) ^ ((m>>2)&3)), 16B chunks.
  {
    const int Wv  = R >> 5;          // 0..7 (matches GEMM-2's kt)
    const int S   = (R >> 4) & 1;
    const int qB  = (2 * S + (q >> 1)) & 3;
    const int swz = (m & 3) ^ ((m >> 2) & 3);
    unsigned short* whP = whG + (size_t)g * (NN * FO);
    #pragma unroll
    for (int nt = 0; nt < 4; ++nt) {
      int chunk = ((Wv * 4 + nt) * 16 + m) * 4 + (qB ^ swz);
      uint2 wrv;
      wrv.x = pack2(acc[nt][0], acc[nt][1]);
      wrv.y = pack2(acc[nt][2], acc[nt][3]);
      *(uint2*)((char*)whP + chunk * 16 + (q & 1) * 8) = wrv;
    }
  }
}

// ---------------- Kernel B: softmax + GEMM-2 + elu.
// 256 threads = 4 waves; each wave owns 16 attention rows; grid = 2048.
// T14 async-stage: whG (32 KB/graph, shared by all 4 waves) is issued as
// register loads UP FRONT, held through softmax (hides HBM latency — the
// 256 MiB re-poison flushes L3 so whG reads are HBM), written to LDS after
// softmax, then the MFMA loop reads fragments via ds_read_b128. This also
// structurally forces >32 VGPRs, preventing the compiler's serialized
// re-fusion seen in round 5 (VGPR=32, 36 us of exposed vmcnt latency).
__global__ __launch_bounds__(256, 2)
void gat_attn(const unsigned short* __restrict__ whG,
              const float* __restrict__ wh1G, const float* __restrict__ wh2G,
              const float* __restrict__ adj, float* __restrict__ out)
{
  const int bid  = blockIdx.x;
  const int g    = bid >> 2;
  const int qt   = bid & 3;
  const int tid  = threadIdx.x;
  const int lane = tid & 63;
  const int w2   = tid >> 6;
  const int m    = lane & 15;
  const int q    = lane >> 4;
  const int row  = 64 * qt + 16 * w2 + m;   // this lane's attention row

  __shared__ __align__(16) unsigned short sWh[NN * FO]; // 32 KB staged Wh

  const unsigned short* __restrict__ whP = whG + (size_t)g * (NN * FO);
  const float* __restrict__ wh2B = wh2G + g * NN;
  const float* __restrict__ adjR = adj + (size_t)row * NN;

  // ---- stage 1: issue this thread's 8 x 16B slice of whG (linear copy).
  // Wave w2, iter i covers chunks w2*512 + i*64 + lane -> coalesced 1KB/wave.
  uint4 st[8];
  #pragma unroll
  for (int i = 0; i < 8; ++i)
    st[i] = *(const uint4*)(whP + (size_t)(w2 * 512 + i * 64 + lane) * 8);

  const float w1 = wh1G[g * NN + row];      // pre-scaled by log2e

  // ---- softmax (loads are L2-hot: wh2B 1KB/graph, adj rows shared across g)
  s16x8 A[8];                               // alpha, B-fragment layout
  float sum = 0.f;
  #pragma unroll
  for (int kt = 0; kt < 8; ++kt) {
    int j0 = kt * 32 + q * 8;
    float4 w20 = *(const float4*)&wh2B[j0];
    float4 w21 = *(const float4*)&wh2B[j0 + 4];
    float4 ad0 = *(const float4*)&adjR[j0];
    float4 ad1 = *(const float4*)&adjR[j0 + 4];
    float p[8];
    const float w2e[8] = {w20.x, w20.y, w20.z, w20.w, w21.x, w21.y, w21.z, w21.w};
    const float ade[8] = {ad0.x, ad0.y, ad0.z, ad0.w, ad1.x, ad1.y, ad1.z, ad1.w};
    #pragma unroll
    for (int e = 0; e < 8; ++e) {
      float l = w1 + w2e[e];
      l = fmaxf(l, 0.01f * l);               // leaky-relu (log2e pre-folded)
      float pe = fexp2(l) * ade[e];          // adj is exactly 0.0/1.0 -> mask=mul
      p[e] = pe;
      sum += pe;
    }
    union { unsigned u[4]; s16x8 v; } pk;
    pk.u[0] = pktrunc(p[0], p[1]);
    pk.u[1] = pktrunc(p[2], p[3]);
    pk.u[2] = pktrunc(p[4], p[5]);
    pk.u[3] = pktrunc(p[6], p[7]);
    A[kt] = pk.v;
  }
  sum += __shfl_xor(sum, 16);
  sum += __shfl_xor(sum, 32);
  const float inv = __builtin_amdgcn_rcpf(sum);

  // ---- stage 2: staged regs -> LDS (loads have had all of softmax to land)
  #pragma unroll
  for (int i = 0; i < 8; ++i)
    *(uint4*)&sWh[(size_t)(w2 * 512 + i * 64 + lane) * 8] = st[i];
  __syncthreads();

  // ---- GEMM-2 swapped: D = Wh^T(A-op) @ alpha^T(B-op), fragments from LDS.
  // Read swizzle matches gat_wh's write swizzle -> 2-way banks (free, m136).
  const int swz = (m & 3) ^ ((m >> 2) & 3);
  f32x4 acc[4];
  #pragma unroll
  for (int ot = 0; ot < 4; ++ot) acc[ot] = (f32x4){0.f, 0.f, 0.f, 0.f};
  #pragma unroll
  for (int kt = 0; kt < 8; ++kt) {
    #pragma unroll
    for (int ot = 0; ot < 4; ++ot) {
      int chunk = ((kt * 4 + ot) * 16 + m) * 4 + (q ^ swz);
      s16x8 whf = *(const s16x8*)&sWh[chunk * 8];
      acc[ot] = __builtin_amdgcn_mfma_f32_16x16x32_bf16(whf, A[kt], acc[ot], 0, 0, 0);
    }
  }

  // epilogue: lane(m,q) holds out[row][16ot+4q .. +3]
  float* outB = out + (size_t)g * NN * FO;
  #pragma unroll
  for (int ot = 0; ot < 4; ++ot) {
    float4 v4;
    float* vp = (float*)&v4;
    #pragma unroll
    for (int r = 0; r < 4; ++r) {
      float v = acc[ot][r] * inv;
      float ev = fexp2(v * LOG2E) - 1.f;
      vp[r] = v > 0.f ? v : ev;
    }
    *(float4*)&outB[row * FO + 16 * ot + 4 * q] = v4;
  }
}

extern "C" void kernel_launch(void* const* d_in, const int* in_sizes, int n_in,
                              void* d_out, int out_size, void* d_ws, size_t ws_size,
                              hipStream_t stream) {
  const float* h   = (const float*)d_in[0];
  const float* W   = (const float*)d_in[1];
  const float* a   = (const float*)d_in[2];
  const float* adj = (const float*)d_in[3];
  float* out = (float*)d_out;

  // workspace layout (all 16B-aligned):
  //   wh1G : 512 KiB   (fp32, pre-scaled by log2e)
  //   wh2G : 512 KiB
  //   whG  : 16 MiB    (bf16 Wh, frag-chunk layout, 32 KB/graph)
  char* ws = (char*)d_ws;
  float*           wh1G = (float*)(ws);
  float*           wh2G = (float*)(ws + 524288);
  unsigned short*  whG  = (unsigned short*)(ws + 2 * 524288);

  gat_wh  <<<dim3(2048), dim3(256), 0, stream>>>(h, W, a, whG, wh1G, wh2G);
  gat_attn<<<dim3(2048), dim3(256), 0, stream>>>(whG, wh1G, wh2G, adj, out);
}

// Round 7
// 134.042 us; speedup vs baseline: 1.1311x; 1.0053x over previous
//
#include <hip/hip_runtime.h>
#include <hip/hip_bf16.h>

#define NN 256
#define FI 128
#define FO 64
#define LOG2E 1.4426950408889634f

typedef short s16x8 __attribute__((ext_vector_type(8)));
typedef float f32x4 __attribute__((ext_vector_type(4)));

__device__ __forceinline__ unsigned f2bf1(float x) {
  union { float f; unsigned u; } v; v.f = x;
  unsigned r = v.u + 0x7FFFu + ((v.u >> 16) & 1u);
  return r >> 16;
}
__device__ __forceinline__ unsigned pack2(float a, float b) {
  return f2bf1(a) | (f2bf1(b) << 16);
}
// one-instruction bf16x2 pack (truncation) via v_perm_b32 — alpha only
__device__ __forceinline__ unsigned pktrunc(float lo, float hi) {
  union { float f; unsigned u; } a, b; a.f = hi; b.f = lo;
  return __builtin_amdgcn_perm(a.u, b.u, 0x07060302u);
}
__device__ __forceinline__ float fexp2(float x) {
#if __has_builtin(__builtin_amdgcn_exp2f)
  return __builtin_amdgcn_exp2f(x);
#else
  return exp2f(x);
#endif
}

// ---------------- Kernel A: GEMM-1. One barrier, 17 KB LDS (W^T staging).
// 256 threads = 4 waves; each wave owns ONE 16-row subtile of Wh.
// grid = 512 graphs * 4 quarters. Writes:
//   whG  : bf16 Wh in GEMM-2 fragment-chunk layout (32 KB/graph),
//          q-slot swizzled by (m&3)^((m>>2)&3) so kernel B's LDS reads are 2-way
//   wh1G/wh2G : fp32, pre-scaled by LOG2E
__global__ __launch_bounds__(256, 4)
void gat_wh(const float* __restrict__ h, const float* __restrict__ W,
            const float* __restrict__ a,
            unsigned short* __restrict__ whG,
            float* __restrict__ wh1G, float* __restrict__ wh2G)
{
  const int bid  = blockIdx.x;
  const int g    = bid >> 2;          // graph (b*t)
  const int qt   = bid & 3;           // quarter: rows 64*qt..+63
  const int tid  = threadIdx.x;
  const int lane = tid & 63;
  const int w2   = tid >> 6;          // wave 0..3
  const int m    = lane & 15;
  const int q    = lane >> 4;
  const int R    = 64 * qt + 16 * w2; // wave's 16-row base (16-aligned)

  __shared__ __align__(16) unsigned short sWT[64 * 136]; // bf16 W^T [o][k], padded

  const float* __restrict__ hB = h + (size_t)g * NN * FI;

  // 16 rows of h: lane (m,q) -> row R+m, cols kt*32 + q*8 (+0,+4). Issued up front.
  float4 x[4][2];
  #pragma unroll
  for (int kt = 0; kt < 4; ++kt) {
    const float* p = hB + (size_t)(R + m) * FI + kt * 32 + q * 8;
    x[kt][0] = *(const float4*)p;
    x[kt][1] = *(const float4*)(p + 4);
  }

  // Stage W (fp32 [k][o], 32 KB, L2-hot) -> sWT bf16 [o][k].
  // k-paired: read rows k,k+1 same o-quad, pack along k -> 16 ds_write_b32
  // per thread (was 32 ds_write_b16). 4 iters x 256 thr x (2k x 4o) = 8192.
  #pragma unroll
  for (int it = 0; it < 4; ++it) {
    int idx = it * 256 + tid;          // 0..1023
    int k   = (idx >> 4) << 1;         // even k: 0,2,..,126
    int o   = (idx & 15) << 2;         // 0,4,..,60
    float4 wa = *(const float4*)&W[k * FO + o];
    float4 wb = *(const float4*)&W[(k + 1) * FO + o];
    *(unsigned*)&sWT[(o + 0) * 136 + k] = pack2(wa.x, wb.x);
    *(unsigned*)&sWT[(o + 1) * 136 + k] = pack2(wa.y, wb.y);
    *(unsigned*)&sWT[(o + 2) * 136 + k] = pack2(wa.z, wb.z);
    *(unsigned*)&sWT[(o + 3) * 136 + k] = pack2(wa.w, wb.w);
  }

  // a-vector values (512 B, L1-broadcast)
  float a1v[4], a2v[4];
  #pragma unroll
  for (int nt = 0; nt < 4; ++nt) {
    a1v[nt] = a[16 * nt + m];
    a2v[nt] = a[FO + 16 * nt + m];
  }

  s16x8 af[4];
  #pragma unroll
  for (int kt = 0; kt < 4; ++kt) {
    union { unsigned u[4]; s16x8 v; } pk;
    pk.u[0] = pack2(x[kt][0].x, x[kt][0].y);
    pk.u[1] = pack2(x[kt][0].z, x[kt][0].w);
    pk.u[2] = pack2(x[kt][1].x, x[kt][1].y);
    pk.u[3] = pack2(x[kt][1].z, x[kt][1].w);
    af[kt] = pk.v;
  }

  __syncthreads();   // sWT ready

  f32x4 acc[4];
  #pragma unroll
  for (int nt = 0; nt < 4; ++nt) acc[nt] = (f32x4){0.f, 0.f, 0.f, 0.f};
  #pragma unroll
  for (int kt = 0; kt < 4; ++kt)
    #pragma unroll
    for (int nt = 0; nt < 4; ++nt) {
      s16x8 bf = *(const s16x8*)&sWT[(16 * nt + m) * 136 + kt * 32 + q * 8];
      acc[nt] = __builtin_amdgcn_mfma_f32_16x16x32_bf16(af[kt], bf, acc[nt], 0, 0, 0);
    }

  // wh1/wh2 epilogue (acc[nt][r] = Wh[R+4q+r][16nt+m]); store x log2e
  {
    float p1[4] = {0.f,0.f,0.f,0.f}, p2[4] = {0.f,0.f,0.f,0.f};
    #pragma unroll
    for (int nt = 0; nt < 4; ++nt) {
      #pragma unroll
      for (int r = 0; r < 4; ++r) { p1[r] += acc[nt][r] * a1v[nt]; p2[r] += acc[nt][r] * a2v[nt]; }
    }
    #pragma unroll
    for (int off = 1; off < 16; off <<= 1)
      #pragma unroll
      for (int r = 0; r < 4; ++r) {
        p1[r] += __shfl_xor(p1[r], off);
        p2[r] += __shfl_xor(p2[r], off);
      }
    if (m == 0) {
      *(float4*)&wh1G[g * NN + R + 4 * q] =
          make_float4(p1[0]*LOG2E, p1[1]*LOG2E, p1[2]*LOG2E, p1[3]*LOG2E);
      *(float4*)&wh2G[g * NN + R + 4 * q] =
          make_float4(p2[0]*LOG2E, p2[1]*LOG2E, p2[2]*LOG2E, p2[3]*LOG2E);
    }
  }

  // Wh -> global frag-chunk layout, q-slot PRE-SWIZZLED for kernel B's LDS
  // bank pattern (rule #21: swizzled source + linear LDS copy + swizzled read).
  // chunk = ((Wv*4+nt)*16+m)*4 + (qB ^ (m&3) ^ ((m>>2)&3)), 16B chunks.
  {
    const int Wv  = R >> 5;          // 0..7 (matches GEMM-2's kt)
    const int S   = (R >> 4) & 1;
    const int qB  = (2 * S + (q >> 1)) & 3;
    const int swz = (m & 3) ^ ((m >> 2) & 3);
    unsigned short* whP = whG + (size_t)g * (NN * FO);
    #pragma unroll
    for (int nt = 0; nt < 4; ++nt) {
      int chunk = ((Wv * 4 + nt) * 16 + m) * 4 + (qB ^ swz);
      uint2 wrv;
      wrv.x = pack2(acc[nt][0], acc[nt][1]);
      wrv.y = pack2(acc[nt][2], acc[nt][3]);
      *(uint2*)((char*)whP + chunk * 16 + (q & 1) * 8) = wrv;
    }
  }
}

// ---------------- Kernel B: softmax + GEMM-2 + elu.
// 512 threads = 8 waves; each wave owns 16 attention rows -> one block covers
// HALF a graph; grid = 1024. The graph's 32 KB whG is staged ONCE per block
// (was 4x per graph): T14 async-stage — 4 uint4 register loads issued UP
// FRONT, held through softmax (hides HBM/L3 latency), written to LDS after,
// MFMA reads via ds_read_b128 with the matching swizzle (2-way banks, free).
__global__ __launch_bounds__(512)
__attribute__((amdgpu_waves_per_eu(3, 4)))
void gat_attn(const unsigned short* __restrict__ whG,
              const float* __restrict__ wh1G, const float* __restrict__ wh2G,
              const float* __restrict__ adj, float* __restrict__ out)
{
  const int bid  = blockIdx.x;
  const int g    = bid >> 1;
  const int hf   = bid & 1;                 // which 128 rows this block owns
  const int tid  = threadIdx.x;
  const int lane = tid & 63;
  const int w2   = tid >> 6;                // wave 0..7
  const int m    = lane & 15;
  const int q    = lane >> 4;
  const int row  = 128 * hf + 16 * w2 + m;  // this lane's attention row

  __shared__ __align__(16) unsigned short sWh[NN * FO]; // 32 KB staged Wh

  const unsigned short* __restrict__ whP = whG + (size_t)g * (NN * FO);
  const float* __restrict__ wh2B = wh2G + g * NN;
  const float* __restrict__ adjR = adj + (size_t)row * NN;

  // ---- stage 1: issue this thread's 4 x 16B slice of whG (linear copy,
  // 8 KB per wave-instruction, perfectly coalesced).
  uint4 st[4];
  #pragma unroll
  for (int i = 0; i < 4; ++i)
    st[i] = *(const uint4*)(whP + (size_t)(i * 512 + tid) * 8);

  const float w1 = wh1G[g * NN + row];      // pre-scaled by log2e

  // ---- softmax (wh2B 1KB/graph, adj rows shared across graphs: L2-hot)
  s16x8 A[8];                               // alpha, B-fragment layout
  float sum = 0.f;
  #pragma unroll
  for (int kt = 0; kt < 8; ++kt) {
    int j0 = kt * 32 + q * 8;
    float4 w20 = *(const float4*)&wh2B[j0];
    float4 w21 = *(const float4*)&wh2B[j0 + 4];
    float4 ad0 = *(const float4*)&adjR[j0];
    float4 ad1 = *(const float4*)&adjR[j0 + 4];
    float p[8];
    const float w2e[8] = {w20.x, w20.y, w20.z, w20.w, w21.x, w21.y, w21.z, w21.w};
    const float ade[8] = {ad0.x, ad0.y, ad0.z, ad0.w, ad1.x, ad1.y, ad1.z, ad1.w};
    #pragma unroll
    for (int e = 0; e < 8; ++e) {
      float l = w1 + w2e[e];
      l = fmaxf(l, 0.01f * l);               // leaky-relu (log2e pre-folded)
      float pe = fexp2(l) * ade[e];          // adj is exactly 0.0/1.0 -> mask=mul
      p[e] = pe;
      sum += pe;
    }
    union { unsigned u[4]; s16x8 v; } pk;
    pk.u[0] = pktrunc(p[0], p[1]);
    pk.u[1] = pktrunc(p[2], p[3]);
    pk.u[2] = pktrunc(p[4], p[5]);
    pk.u[3] = pktrunc(p[6], p[7]);
    A[kt] = pk.v;
  }
  sum += __shfl_xor(sum, 16);
  sum += __shfl_xor(sum, 32);
  const float inv = __builtin_amdgcn_rcpf(sum);

  // ---- stage 2: staged regs -> LDS (loads had all of softmax to land)
  #pragma unroll
  for (int i = 0; i < 4; ++i)
    *(uint4*)&sWh[(size_t)(i * 512 + tid) * 8] = st[i];
  __syncthreads();

  // ---- GEMM-2 swapped: D = Wh^T(A-op) @ alpha^T(B-op), fragments from LDS.
  // Read swizzle matches gat_wh's write swizzle -> 2-way banks (free, m136).
  const int swz = (m & 3) ^ ((m >> 2) & 3);
  f32x4 acc[4];
  #pragma unroll
  for (int ot = 0; ot < 4; ++ot) acc[ot] = (f32x4){0.f, 0.f, 0.f, 0.f};
  #pragma unroll
  for (int kt = 0; kt < 8; ++kt) {
    #pragma unroll
    for (int ot = 0; ot < 4; ++ot) {
      int chunk = ((kt * 4 + ot) * 16 + m) * 4 + (q ^ swz);
      s16x8 whf = *(const s16x8*)&sWh[chunk * 8];
      acc[ot] = __builtin_amdgcn_mfma_f32_16x16x32_bf16(whf, A[kt], acc[ot], 0, 0, 0);
    }
  }

  // epilogue: lane(m,q) holds out[row][16ot+4q .. +3]
  float* outB = out + (size_t)g * NN * FO;
  #pragma unroll
  for (int ot = 0; ot < 4; ++ot) {
    float4 v4;
    float* vp = (float*)&v4;
    #pragma unroll
    for (int r = 0; r < 4; ++r) {
      float v = acc[ot][r] * inv;
      float ev = fexp2(v * LOG2E) - 1.f;
      vp[r] = v > 0.f ? v : ev;
    }
    *(float4*)&outB[row * FO + 16 * ot + 4 * q] = v4;
  }
}

extern "C" void kernel_launch(void* const* d_in, const int* in_sizes, int n_in,
                              void* d_out, int out_size, void* d_ws, size_t ws_size,
                              hipStream_t stream) {
  const float* h   = (const float*)d_in[0];
  const float* W   = (const float*)d_in[1];
  const float* a   = (const float*)d_in[2];
  const float* adj = (const float*)d_in[3];
  float* out = (float*)d_out;

  // workspace layout (all 16B-aligned):
  //   wh1G : 512 KiB   (fp32, pre-scaled by log2e)
  //   wh2G : 512 KiB
  //   whG  : 16 MiB    (bf16 Wh, frag-chunk layout, 32 KB/graph)
  char* ws = (char*)d_ws;
  float*           wh1G = (float*)(ws);
  float*           wh2G = (float*)(ws + 524288);
  unsigned short*  whG  = (unsigned short*)(ws + 2 * 524288);

  gat_wh  <<<dim3(2048), dim3(256), 0, stream>>>(h, W, a, whG, wh1G, wh2G);
  gat_attn<<<dim3(1024), dim3(512), 0, stream>>>(whG, wh1G, wh2G, adj, out);
}